// Round 4
// baseline (157.697 us; speedup 1.0000x reference)
//
#include <hip/hip_runtime.h>
#include <hip/hip_bf16.h>

typedef __bf16 bf16;
typedef __attribute__((ext_vector_type(4))) __bf16 bf16x4;
typedef __attribute__((ext_vector_type(8))) __bf16 bf16x8;
typedef __attribute__((ext_vector_type(4))) float f32x4;
typedef __attribute__((ext_vector_type(4))) short s16x4;

#define T_SEQ 4096
#define D_EMB 1024
#define HS 64

#if __has_builtin(__builtin_amdgcn_mfma_f32_16x16x16bf16_1k)
#define MFMA16_OK 1
#else
#define MFMA16_OK 0
#endif

__device__ __forceinline__ float fexp2(float x) {
#if __has_builtin(__builtin_amdgcn_exp2f)
    return __builtin_amdgcn_exp2f(x);
#else
    return exp2f(x);
#endif
}

#if MFMA16_OK
__device__ __forceinline__ s16x4 bc4(bf16x4 v) {
    return __builtin_bit_cast(s16x4, v);
}
#endif

// ---------------------------------------------------------------------------
// Kernel 0: cast Wk|Wv (fp32, 64x1024 each) -> bf16 workspace copies.
// ---------------------------------------------------------------------------
__global__ __launch_bounds__(256) void wcast_kernel(
    const float* __restrict__ Wk, const float* __restrict__ Wv,
    bf16* __restrict__ wbf)   // [128][1024]
{
    const int t = blockIdx.x * 256 + threadIdx.x;
    const int base = t * 8;
    const float* src = (base < 65536) ? (Wk + base) : (Wv + base - 65536);
    float4 f0 = *(const float4*)(src);
    float4 f1 = *(const float4*)(src + 4);
    bf16x8 o = {(__bf16)f0.x, (__bf16)f0.y, (__bf16)f0.z, (__bf16)f0.w,
                (__bf16)f1.x, (__bf16)f1.y, (__bf16)f1.z, (__bf16)f1.w};
    *(bf16x8*)(wbf + base) = o;
}

// ---------------------------------------------------------------------------
// Kernel 1: staged-LDS projection GEMM, BM=32, full N=128, no split-K.
// (unchanged this round — isolating the attn restructure for attribution)
// ---------------------------------------------------------------------------
__global__ __launch_bounds__(256, 2) void proj_kernel(
    const float* __restrict__ x,    // [16384][1024] fp32
    const bf16* __restrict__ wbf,   // [128][1024] bf16 (Wk rows 0-63, Wv 64-127)
    bf16* __restrict__ kmat,        // [16384][64]
    bf16* __restrict__ qvmat,       // [16384][64]
    bf16* __restrict__ qvT)         // [4][64][4096]
{
    __shared__ bf16 xs[32][72];     // 4.6 KB  (rows padded to 144 B)
    __shared__ bf16 wsh[128][72];   // 18.4 KB
    __shared__ bf16 vt[64][40];     // 5 KB    (qv transpose tile, 80 B rows)

    const int tid  = threadIdx.x;
    const int lane = tid & 63;
    const int wave = tid >> 6;
    const int col  = lane & 15;
    const int quad = lane >> 4;
    const int rowbase = blockIdx.x * 32;

    f32x4 acc[2][2];
#pragma unroll
    for (int mt = 0; mt < 2; ++mt)
#pragma unroll
        for (int nt = 0; nt < 2; ++nt) acc[mt][nt] = {0.f, 0.f, 0.f, 0.f};

    // register prefetch of chunk 0
    float4 xn[2];
    bf16x8 wn[4];
    {
#pragma unroll
        for (int p = 0; p < 2; ++p) {
            const int idx = p * 256 + tid;          // 512 float4s: x 32x64
            const int xr  = idx >> 4;
            const int c4  = (idx & 15) * 4;
            xn[p] = *(const float4*)(x + (size_t)(rowbase + xr) * D_EMB + c4);
        }
#pragma unroll
        for (int p = 0; p < 4; ++p) {
            const int idx = p * 256 + tid;          // 1024 bf16x8s: W 128x64
            const int wr  = idx >> 3;
            const int off = (idx & 7) * 8;
            wn[p] = *(const bf16x8*)(wbf + (size_t)wr * D_EMB + off);
        }
    }

#pragma unroll 1
    for (int c = 0; c < 16; ++c) {
        // ---- write prefetched chunk into LDS ----
#pragma unroll
        for (int p = 0; p < 2; ++p) {
            const int idx = p * 256 + tid;
            const int xr  = idx >> 4;
            const int c4  = (idx & 15) * 4;
            bf16x4 v = {(__bf16)xn[p].x, (__bf16)xn[p].y,
                        (__bf16)xn[p].z, (__bf16)xn[p].w};
            *(bf16x4*)&xs[xr][c4] = v;
        }
#pragma unroll
        for (int p = 0; p < 4; ++p) {
            const int idx = p * 256 + tid;
            const int wr  = idx >> 3;
            const int off = (idx & 7) * 8;
            *(bf16x8*)&wsh[wr][off] = wn[p];
        }
        __syncthreads();

        // ---- issue next chunk's loads (hidden behind compute) ----
        if (c < 15) {
            const int k0 = (c + 1) * 64;
#pragma unroll
            for (int p = 0; p < 2; ++p) {
                const int idx = p * 256 + tid;
                const int xr  = idx >> 4;
                const int c4  = (idx & 15) * 4;
                xn[p] = *(const float4*)(x + (size_t)(rowbase + xr) * D_EMB + k0 + c4);
            }
#pragma unroll
            for (int p = 0; p < 4; ++p) {
                const int idx = p * 256 + tid;
                const int wr  = idx >> 3;
                const int off = (idx & 7) * 8;
                wn[p] = *(const bf16x8*)(wbf + (size_t)wr * D_EMB + k0 + off);
            }
        }

        // ---- compute chunk from LDS ----
#pragma unroll
        for (int s = 0; s < 2; ++s) {
            bf16x8 af[2];
#pragma unroll
            for (int mt = 0; mt < 2; ++mt)
                af[mt] = *(const bf16x8*)&xs[mt * 16 + col][s * 32 + quad * 8];
            bf16x8 bfr[2];
#pragma unroll
            for (int nt = 0; nt < 2; ++nt)
                bfr[nt] = *(const bf16x8*)&wsh[wave * 32 + nt * 16 + col][s * 32 + quad * 8];
#pragma unroll
            for (int mt = 0; mt < 2; ++mt)
#pragma unroll
                for (int nt = 0; nt < 2; ++nt)
                    acc[mt][nt] = __builtin_amdgcn_mfma_f32_16x16x32_bf16(
                        af[mt], bfr[nt], acc[mt][nt], 0, 0, 0);
        }
        __syncthreads();
    }

    // ---- epilogue: C layout col=lane&15, row=quad*4+reg ----
#pragma unroll
    for (int mt = 0; mt < 2; ++mt)
#pragma unroll
        for (int nt = 0; nt < 2; ++nt) {
            const int gcol = wave * 32 + nt * 16 + col;
#pragma unroll
            for (int r = 0; r < 4; ++r) {
                const int grow = rowbase + mt * 16 + quad * 4 + r;
                const int ltt  = mt * 16 + quad * 4 + r;
                bf16 bv = (bf16)acc[mt][nt][r];
                if (gcol < 64) {
                    kmat[(size_t)grow * HS + gcol] = bv;
                } else {
                    qvmat[(size_t)grow * HS + (gcol - 64)] = bv;
                    vt[gcol - 64][ltt] = bv;     // transpose tile in LDS
                }
            }
        }
    __syncthreads();

    // qvT store: thread -> (h = tid>>2, 8-elem segment), 16 B coalesced rows
    {
        const int h   = tid >> 2;
        const int seg = (tid & 3) * 8;
        bf16x8 v = *(const bf16x8*)&vt[h][seg];
        const int bb  = rowbase >> 12;
        const int tt0 = (rowbase & (T_SEQ - 1)) + seg;
        *(bf16x8*)(qvT + ((size_t)bb * HS + h) * T_SEQ + tt0) = v;
    }
}

// ---------------------------------------------------------------------------
// Kernel 2: causal attention, swapped QK^T, 32 q-rows PER WAVE (two 16-col
// groups at q0 and q0+64). Block = 4 waves = 128 q rows; K/V staging, both
// barriers, and all Kt/Vt LDS reads now serve 2x the output. k-slots of 6
// chunks -> 187 jobs/batch, grid 748, 3 blocks/CU (all co-resident).
// ---------------------------------------------------------------------------
__global__ __launch_bounds__(256, 3) void attn_kernel(
    const bf16* __restrict__ kmat,   // [B*T][64]
    const bf16* __restrict__ qvmat,  // [B*T][64]
    const bf16* __restrict__ qvT,    // [B][64][T]
    float* __restrict__ out,         // [B*T][64] raw O partial, slot 0
    float* __restrict__ o_parts,     // [10][B*T][64] raw O partials, slots 1-10
    float* __restrict__ l_parts)     // [11][B*T] l partials
{
    __shared__ bf16 Kt[64][72];      // 9.2 KB
    __shared__ bf16 Vt[64][72];      // 9.2 KB
#if !MFMA16_OK
    __shared__ bf16 plds[4][16][40]; // fallback P staging (80 B rows)
#endif

    const int tid  = threadIdx.x;
    const int lane = tid & 63;
    const int wave = tid >> 6;
    const int col  = lane & 15;
    const int quad = lane >> 4;

    // job decode: 187 jobs/batch, heavy qb2 first. qb2 in 0..31 owns 128 q
    // rows and nctot = 2*qb2+2 chunks, split into ceil(nctot/6) slots.
    const int b = blockIdx.x / 187;
    int r = blockIdx.x - b * 187;
    int qb2 = 31, jc = 0;
#pragma unroll 1
    for (int q = 31; q >= 0; --q) {
        const int nj = (2 * q + 7) / 6;          // ceil((2q+2)/6)
        if (r < nj) { qb2 = q; jc = r; break; }
        r -= nj;
    }
    const int nctot = 2 * qb2 + 2;
    const int cbeg  = jc * 6;
    const int cend  = (nctot < cbeg + 6) ? nctot : cbeg + 6;

    const bf16* qvb = qvmat + (size_t)b * T_SEQ * HS;
    const bf16* kb  = kmat  + (size_t)b * T_SEQ * HS;
    const bf16* vTb = qvT   + (size_t)b * HS * T_SEQ;

    const int q0 = qb2 * 128 + wave * 16;        // lower group
    const int q1 = q0 + 64;                      // upper group

    // Q fragments (B-operand, col=lane&15): two d-halves per group
    bf16x8 qf0a = *(const bf16x8*)(qvb + (size_t)(q0 + col) * HS + quad * 8);
    bf16x8 qf0b = *(const bf16x8*)(qvb + (size_t)(q0 + col) * HS + 32 + quad * 8);
    bf16x8 qf1a = *(const bf16x8*)(qvb + (size_t)(q1 + col) * HS + quad * 8);
    bf16x8 qf1b = *(const bf16x8*)(qvb + (size_t)(q1 + col) * HS + 32 + quad * 8);

    f32x4 o0[4], o1[4];
#pragma unroll
    for (int h = 0; h < 4; ++h) { o0[h] = {0.f, 0.f, 0.f, 0.f}; o1[h] = {0.f, 0.f, 0.f, 0.f}; }
    float lsum0 = 0.f, lsum1 = 0.f;

    const float sc = 0.125f * 1.44269504088896f;

    // register prefetch of first chunk
    bf16x8 kn[2], vn[2];
    {
        const int kc = cbeg * 64;
#pragma unroll
        for (int it = 0; it < 2; ++it) {
            const int idx = it * 256 + tid;
            const int kr  = idx >> 3;
            const int off = (idx & 7) * 8;
            kn[it] = *(const bf16x8*)(kb + (size_t)kc * HS + idx * 8);
            vn[it] = *(const bf16x8*)(vTb + (size_t)kr * T_SEQ + kc + off);
        }
    }

#pragma unroll 1
    for (int c = cbeg; c < cend; ++c) {
        // ---- write prefetched chunk into LDS ----
#pragma unroll
        for (int it = 0; it < 2; ++it) {
            const int idx = it * 256 + tid;
            const int kr  = idx >> 3;
            const int off = (idx & 7) * 8;
            *(bf16x8*)&Kt[kr][off] = kn[it];
            *(bf16x8*)&Vt[kr][off] = vn[it];
        }
        __syncthreads();

        // ---- issue next chunk's loads (hidden behind compute) ----
        if (c + 1 < cend) {
            const int kcn = (c + 1) * 64;
#pragma unroll
            for (int it = 0; it < 2; ++it) {
                const int idx = it * 256 + tid;
                const int kr  = idx >> 3;
                const int off = (idx & 7) * 8;
                kn[it] = *(const bf16x8*)(kb + (size_t)kcn * HS + idx * 8);
                vn[it] = *(const bf16x8*)(vTb + (size_t)kr * T_SEQ + kcn + off);
            }
        }

        const int kc = c * 64;
#if MFMA16_OK
        // ---- 16-k subtile loop; K frags + V frags shared across both q-groups ----
#pragma unroll
        for (int ks = 0; ks < 4; ++ks) {
            const int gk = kc + 16 * ks;
            if (gk > q1 + 15) break;             // beyond wave's top diagonal

            bf16x8 ka = *(const bf16x8*)&Kt[16 * ks + col][quad * 8];
            bf16x8 kbf = *(const bf16x8*)&Kt[16 * ks + col][32 + quad * 8];

            // group 1 (q1): always active here
            float p1v[4];
            {
                f32x4 a4 = {0.f, 0.f, 0.f, 0.f};
                a4 = __builtin_amdgcn_mfma_f32_16x16x32_bf16(ka,  qf1a, a4, 0, 0, 0);
                a4 = __builtin_amdgcn_mfma_f32_16x16x32_bf16(kbf, qf1b, a4, 0, 0, 0);
#pragma unroll
                for (int i = 0; i < 4; ++i) p1v[i] = fexp2(fmaf(a4[i], sc, -24.f));
            }
            if (gk + 15 > q1) {
#pragma unroll
                for (int i = 0; i < 4; ++i)
                    if (gk + quad * 4 + i > q1 + col) p1v[i] = 0.f;
            }
            lsum1 += (p1v[0] + p1v[1]) + (p1v[2] + p1v[3]);

            // group 0 (q0): active only below its diagonal (wave-uniform test)
            const bool g0 = (gk <= q0 + 15);
            float p0v[4];
            if (g0) {
                f32x4 a4 = {0.f, 0.f, 0.f, 0.f};
                a4 = __builtin_amdgcn_mfma_f32_16x16x32_bf16(ka,  qf0a, a4, 0, 0, 0);
                a4 = __builtin_amdgcn_mfma_f32_16x16x32_bf16(kbf, qf0b, a4, 0, 0, 0);
#pragma unroll
                for (int i = 0; i < 4; ++i) p0v[i] = fexp2(fmaf(a4[i], sc, -24.f));
                if (gk + 15 > q0) {
#pragma unroll
                    for (int i = 0; i < 4; ++i)
                        if (gk + quad * 4 + i > q0 + col) p0v[i] = 0.f;
                }
                lsum0 += (p0v[0] + p0v[1]) + (p0v[2] + p0v[3]);
            }

            bf16x4 pb1 = {(bf16)p1v[0], (bf16)p1v[1], (bf16)p1v[2], (bf16)p1v[3]};
            s16x4 pa1s = bc4(pb1);
            s16x4 pa0s;
            if (g0) {
                bf16x4 pb0 = {(bf16)p0v[0], (bf16)p0v[1], (bf16)p0v[2], (bf16)p0v[3]};
                pa0s = bc4(pb0);
            }
            // PV: V fragment loaded once, feeds both groups
#pragma unroll
            for (int h = 0; h < 4; ++h) {
                bf16x4 vb = *(const bf16x4*)&Vt[h * 16 + col][16 * ks + quad * 4];
                s16x4 vbs = bc4(vb);
                o1[h] = __builtin_amdgcn_mfma_f32_16x16x16bf16_1k(pa1s, vbs, o1[h], 0, 0, 0);
                if (g0)
                    o0[h] = __builtin_amdgcn_mfma_f32_16x16x16bf16_1k(pa0s, vbs, o0[h], 0, 0, 0);
            }
        }
#else
        // ---- fallback: 32-k subtiles, plds staging, 16x16x32 PV ----
#pragma unroll
        for (int st = 0; st < 2; ++st) {
            const int gk = kc + 32 * st;
            if (gk > q1 + 15) break;

            bf16x8 b0 = *(const bf16x8*)&Kt[32 * st + col][quad * 8];
            bf16x8 b1 = *(const bf16x8*)&Kt[32 * st + col][32 + quad * 8];
            const bool t1 = (gk + 16 <= q1 + 15);
            bf16x8 b2, b3;
            if (t1) {
                b2 = *(const bf16x8*)&Kt[32 * st + 16 + col][quad * 8];
                b3 = *(const bf16x8*)&Kt[32 * st + 16 + col][32 + quad * 8];
            }

            // group 1
            float pA[4], pB[4];
            {
                f32x4 a4 = {0.f, 0.f, 0.f, 0.f};
                a4 = __builtin_amdgcn_mfma_f32_16x16x32_bf16(b0, qf1a, a4, 0, 0, 0);
                a4 = __builtin_amdgcn_mfma_f32_16x16x32_bf16(b1, qf1b, a4, 0, 0, 0);
#pragma unroll
                for (int i = 0; i < 4; ++i) pA[i] = fexp2(fmaf(a4[i], sc, -24.f));
            }
            if (t1) {
                f32x4 a4 = {0.f, 0.f, 0.f, 0.f};
                a4 = __builtin_amdgcn_mfma_f32_16x16x32_bf16(b2, qf1a, a4, 0, 0, 0);
                a4 = __builtin_amdgcn_mfma_f32_16x16x32_bf16(b3, qf1b, a4, 0, 0, 0);
#pragma unroll
                for (int i = 0; i < 4; ++i) pB[i] = fexp2(fmaf(a4[i], sc, -24.f));
            } else {
#pragma unroll
                for (int i = 0; i < 4; ++i) pB[i] = 0.f;
            }
            if (gk + 31 > q1) {
#pragma unroll
                for (int i = 0; i < 4; ++i) {
                    if (gk + quad * 4 + i > q1 + col) pA[i] = 0.f;
                    if (t1 && gk + 16 + quad * 4 + i > q1 + col) pB[i] = 0.f;
                }
            }
            lsum1 += (pA[0] + pA[1]) + (pA[2] + pA[3]) + (pB[0] + pB[1]) + (pB[2] + pB[3]);
            {
                bf16x4 w0 = {(bf16)pA[0], (bf16)pA[1], (bf16)pA[2], (bf16)pA[3]};
                bf16x4 w1 = {(bf16)pB[0], (bf16)pB[1], (bf16)pB[2], (bf16)pB[3]};
                *(bf16x4*)&plds[wave][col][quad * 4]      = w0;
                *(bf16x4*)&plds[wave][col][16 + quad * 4] = w1;
            }
            bf16x8 pa1 = *(const bf16x8*)&plds[wave][col][quad * 8];

            // group 0
            const bool g0 = (gk <= q0 + 15);
            bf16x8 pa0;
            if (g0) {
                float qA[4], qB[4];
                {
                    f32x4 a4 = {0.f, 0.f, 0.f, 0.f};
                    a4 = __builtin_amdgcn_mfma_f32_16x16x32_bf16(b0, qf0a, a4, 0, 0, 0);
                    a4 = __builtin_amdgcn_mfma_f32_16x16x32_bf16(b1, qf0b, a4, 0, 0, 0);
#pragma unroll
                    for (int i = 0; i < 4; ++i) qA[i] = fexp2(fmaf(a4[i], sc, -24.f));
                }
                const bool t0 = (gk + 16 <= q0 + 15);
                if (t0) {
                    f32x4 a4 = {0.f, 0.f, 0.f, 0.f};
                    a4 = __builtin_amdgcn_mfma_f32_16x16x32_bf16(b2, qf0a, a4, 0, 0, 0);
                    a4 = __builtin_amdgcn_mfma_f32_16x16x32_bf16(b3, qf0b, a4, 0, 0, 0);
#pragma unroll
                    for (int i = 0; i < 4; ++i) qB[i] = fexp2(fmaf(a4[i], sc, -24.f));
                } else {
#pragma unroll
                    for (int i = 0; i < 4; ++i) qB[i] = 0.f;
                }
                if (gk + 31 > q0) {
#pragma unroll
                    for (int i = 0; i < 4; ++i) {
                        if (gk + quad * 4 + i > q0 + col) qA[i] = 0.f;
                        if (t0 && gk + 16 + quad * 4 + i > q0 + col) qB[i] = 0.f;
                    }
                }
                lsum0 += (qA[0] + qA[1]) + (qA[2] + qA[3]) + (qB[0] + qB[1]) + (qB[2] + qB[3]);
                bf16x4 w0 = {(bf16)qA[0], (bf16)qA[1], (bf16)qA[2], (bf16)qA[3]};
                bf16x4 w1 = {(bf16)qB[0], (bf16)qB[1], (bf16)qB[2], (bf16)qB[3]};
                *(bf16x4*)&plds[wave][col][quad * 4]      = w0;
                *(bf16x4*)&plds[wave][col][16 + quad * 4] = w1;
                pa0 = *(const bf16x8*)&plds[wave][col][quad * 8];
            }

#pragma unroll
            for (int h = 0; h < 4; ++h) {
                bf16x8 vb = *(const bf16x8*)&Vt[h * 16 + col][32 * st + quad * 8];
                o1[h] = __builtin_amdgcn_mfma_f32_16x16x32_bf16(pa1, vb, o1[h], 0, 0, 0);
                if (g0)
                    o0[h] = __builtin_amdgcn_mfma_f32_16x16x32_bf16(pa0, vb, o0[h], 0, 0, 0);
            }
        }
#endif
        __syncthreads();   // protect Kt/Vt before next write
    }

    // ---- epilogue: l row-sums (reduce across quads), unconditional stores ----
    lsum0 += __shfl_xor(lsum0, 16, 64);
    lsum0 += __shfl_xor(lsum0, 32, 64);
    lsum1 += __shfl_xor(lsum1, 16, 64);
    lsum1 += __shfl_xor(lsum1, 32, 64);
    if (quad == 0) {
        l_parts[(size_t)jc * 16384 + (size_t)b * T_SEQ + q0 + col] = lsum0;
        l_parts[(size_t)jc * 16384 + (size_t)b * T_SEQ + q1 + col] = lsum1;
    }

    float* dst = (jc == 0) ? out : (o_parts + (size_t)(jc - 1) * 16384 * HS);
    const size_t rb0 = (size_t)b * T_SEQ + q0 + quad * 4;
    const size_t rb1 = (size_t)b * T_SEQ + q1 + quad * 4;
#pragma unroll
    for (int h = 0; h < 4; ++h)
#pragma unroll
        for (int i = 0; i < 4; ++i) {
            dst[(rb0 + i) * HS + h * 16 + col] = o0[h][i];
            dst[(rb1 + i) * HS + h * 16 + col] = o1[h][i];
        }
}

// ---------------------------------------------------------------------------
// Kernel 3: combine job partials and normalize: out = sum(O_j) / sum(l_j).
// ---------------------------------------------------------------------------
__global__ __launch_bounds__(256) void norm_kernel(
    float* __restrict__ out,
    const float* __restrict__ o_parts,  // [10][B*T][64]
    const float* __restrict__ l_parts)  // [11][B*T]
{
    const int i   = blockIdx.x * 256 + threadIdx.x;
    const int row = i >> 6;
    const int qb2 = (row & 4095) >> 7;
    const int nj  = (2 * qb2 + 7) / 6;          // ceil((2*qb2+2)/6)

    float s = out[i];
    float L = l_parts[row];
    for (int j = 1; j < nj; ++j) {
        s += o_parts[(size_t)(j - 1) * 1048576 + i];
        L += l_parts[(size_t)j * 16384 + row];
    }
    out[i] = s / L;
}

extern "C" void kernel_launch(void* const* d_in, const int* in_sizes, int n_in,
                              void* d_out, int out_size, void* d_ws, size_t ws_size,
                              hipStream_t stream) {
    const float* x  = (const float*)d_in[0];
    const float* Wk = (const float*)d_in[1];
    const float* Wv = (const float*)d_in[2];
    float* out = (float*)d_out;

    bf16* ws    = (bf16*)d_ws;
    bf16* wbf   = ws;                                    // 256 KB
    bf16* kmat  = ws + (size_t)128 * 1024;               // 2 MB
    bf16* qvmat = kmat + (size_t)16384 * 64;             // 2 MB
    bf16* qvT   = qvmat + (size_t)16384 * 64;            // 2 MB
    float* o_parts = (float*)(qvT + (size_t)16384 * 64); // 40 MB (slots 1-10)
    float* l_parts = o_parts + (size_t)10 * 16384 * 64;  // 704 KB

    wcast_kernel<<<64, 256, 0, stream>>>(Wk, Wv, wbf);
    proj_kernel<<<512, 256, 0, stream>>>(x, wbf, kmat, qvmat, qvT);
    attn_kernel<<<748, 256, 0, stream>>>(kmat, qvmat, qvT, out, o_parts, l_parts);
    norm_kernel<<<4096, 256, 0, stream>>>(out, o_parts, l_parts);
}

// Round 5
// 141.656 us; speedup vs baseline: 1.1132x; 1.1132x over previous
//
#include <hip/hip_runtime.h>
#include <hip/hip_bf16.h>

typedef __bf16 bf16;
typedef __attribute__((ext_vector_type(4))) __bf16 bf16x4;
typedef __attribute__((ext_vector_type(8))) __bf16 bf16x8;
typedef __attribute__((ext_vector_type(4))) float f32x4;
typedef __attribute__((ext_vector_type(4))) short s16x4;

#define T_SEQ 4096
#define D_EMB 1024
#define HS 64

#if __has_builtin(__builtin_amdgcn_mfma_f32_16x16x16bf16_1k)
#define MFMA16_OK 1
#else
#define MFMA16_OK 0
#endif

__device__ __forceinline__ float fexp2(float x) {
#if __has_builtin(__builtin_amdgcn_exp2f)
    return __builtin_amdgcn_exp2f(x);
#else
    return exp2f(x);
#endif
}

#if MFMA16_OK
__device__ __forceinline__ s16x4 bc4(bf16x4 v) {
    return __builtin_bit_cast(s16x4, v);
}
#endif

// ---------------------------------------------------------------------------
// Kernel 0: cast Wk|Wv (fp32, 64x1024 each) -> bf16 workspace copies.
// ---------------------------------------------------------------------------
__global__ __launch_bounds__(256) void wcast_kernel(
    const float* __restrict__ Wk, const float* __restrict__ Wv,
    bf16* __restrict__ wbf)   // [128][1024]
{
    const int t = blockIdx.x * 256 + threadIdx.x;
    const int base = t * 8;
    const float* src = (base < 65536) ? (Wk + base) : (Wv + base - 65536);
    float4 f0 = *(const float4*)(src);
    float4 f1 = *(const float4*)(src + 4);
    bf16x8 o = {(__bf16)f0.x, (__bf16)f0.y, (__bf16)f0.z, (__bf16)f0.w,
                (__bf16)f1.x, (__bf16)f1.y, (__bf16)f1.z, (__bf16)f1.w};
    *(bf16x8*)(wbf + base) = o;
}

// ---------------------------------------------------------------------------
// Kernel 1: staged-LDS projection GEMM, BM=32, full N=128, no split-K.
// (unchanged — isolating the attn scheduling change for attribution)
// ---------------------------------------------------------------------------
__global__ __launch_bounds__(256, 2) void proj_kernel(
    const float* __restrict__ x,    // [16384][1024] fp32
    const bf16* __restrict__ wbf,   // [128][1024] bf16 (Wk rows 0-63, Wv 64-127)
    bf16* __restrict__ kmat,        // [16384][64]
    bf16* __restrict__ qvmat,       // [16384][64]
    bf16* __restrict__ qvT)         // [4][64][4096]
{
    __shared__ bf16 xs[32][72];     // 4.6 KB  (rows padded to 144 B)
    __shared__ bf16 wsh[128][72];   // 18.4 KB
    __shared__ bf16 vt[64][40];     // 5 KB    (qv transpose tile, 80 B rows)

    const int tid  = threadIdx.x;
    const int lane = tid & 63;
    const int wave = tid >> 6;
    const int col  = lane & 15;
    const int quad = lane >> 4;
    const int rowbase = blockIdx.x * 32;

    f32x4 acc[2][2];
#pragma unroll
    for (int mt = 0; mt < 2; ++mt)
#pragma unroll
        for (int nt = 0; nt < 2; ++nt) acc[mt][nt] = {0.f, 0.f, 0.f, 0.f};

    // register prefetch of chunk 0
    float4 xn[2];
    bf16x8 wn[4];
    {
#pragma unroll
        for (int p = 0; p < 2; ++p) {
            const int idx = p * 256 + tid;          // 512 float4s: x 32x64
            const int xr  = idx >> 4;
            const int c4  = (idx & 15) * 4;
            xn[p] = *(const float4*)(x + (size_t)(rowbase + xr) * D_EMB + c4);
        }
#pragma unroll
        for (int p = 0; p < 4; ++p) {
            const int idx = p * 256 + tid;          // 1024 bf16x8s: W 128x64
            const int wr  = idx >> 3;
            const int off = (idx & 7) * 8;
            wn[p] = *(const bf16x8*)(wbf + (size_t)wr * D_EMB + off);
        }
    }

#pragma unroll 1
    for (int c = 0; c < 16; ++c) {
        // ---- write prefetched chunk into LDS ----
#pragma unroll
        for (int p = 0; p < 2; ++p) {
            const int idx = p * 256 + tid;
            const int xr  = idx >> 4;
            const int c4  = (idx & 15) * 4;
            bf16x4 v = {(__bf16)xn[p].x, (__bf16)xn[p].y,
                        (__bf16)xn[p].z, (__bf16)xn[p].w};
            *(bf16x4*)&xs[xr][c4] = v;
        }
#pragma unroll
        for (int p = 0; p < 4; ++p) {
            const int idx = p * 256 + tid;
            const int wr  = idx >> 3;
            const int off = (idx & 7) * 8;
            *(bf16x8*)&wsh[wr][off] = wn[p];
        }
        __syncthreads();

        // ---- issue next chunk's loads (hidden behind compute) ----
        if (c < 15) {
            const int k0 = (c + 1) * 64;
#pragma unroll
            for (int p = 0; p < 2; ++p) {
                const int idx = p * 256 + tid;
                const int xr  = idx >> 4;
                const int c4  = (idx & 15) * 4;
                xn[p] = *(const float4*)(x + (size_t)(rowbase + xr) * D_EMB + k0 + c4);
            }
#pragma unroll
            for (int p = 0; p < 4; ++p) {
                const int idx = p * 256 + tid;
                const int wr  = idx >> 3;
                const int off = (idx & 7) * 8;
                wn[p] = *(const bf16x8*)(wbf + (size_t)wr * D_EMB + k0 + off);
            }
        }

        // ---- compute chunk from LDS ----
#pragma unroll
        for (int s = 0; s < 2; ++s) {
            bf16x8 af[2];
#pragma unroll
            for (int mt = 0; mt < 2; ++mt)
                af[mt] = *(const bf16x8*)&xs[mt * 16 + col][s * 32 + quad * 8];
            bf16x8 bfr[2];
#pragma unroll
            for (int nt = 0; nt < 2; ++nt)
                bfr[nt] = *(const bf16x8*)&wsh[wave * 32 + nt * 16 + col][s * 32 + quad * 8];
#pragma unroll
            for (int mt = 0; mt < 2; ++mt)
#pragma unroll
                for (int nt = 0; nt < 2; ++nt)
                    acc[mt][nt] = __builtin_amdgcn_mfma_f32_16x16x32_bf16(
                        af[mt], bfr[nt], acc[mt][nt], 0, 0, 0);
        }
        __syncthreads();
    }

    // ---- epilogue: C layout col=lane&15, row=quad*4+reg ----
#pragma unroll
    for (int mt = 0; mt < 2; ++mt)
#pragma unroll
        for (int nt = 0; nt < 2; ++nt) {
            const int gcol = wave * 32 + nt * 16 + col;
#pragma unroll
            for (int r = 0; r < 4; ++r) {
                const int grow = rowbase + mt * 16 + quad * 4 + r;
                const int ltt  = mt * 16 + quad * 4 + r;
                bf16 bv = (bf16)acc[mt][nt][r];
                if (gcol < 64) {
                    kmat[(size_t)grow * HS + gcol] = bv;
                } else {
                    qvmat[(size_t)grow * HS + (gcol - 64)] = bv;
                    vt[gcol - 64][ltt] = bv;     // transpose tile in LDS
                }
            }
        }
    __syncthreads();

    // qvT store: thread -> (h = tid>>2, 8-elem segment), 16 B coalesced rows
    {
        const int h   = tid >> 2;
        const int seg = (tid & 3) * 8;
        bf16x8 v = *(const bf16x8*)&vt[h][seg];
        const int bb  = rowbase >> 12;
        const int tt0 = (rowbase & (T_SEQ - 1)) + seg;
        *(bf16x8*)(qvT + ((size_t)bb * HS + h) * T_SEQ + tt0) = v;
    }
}

// ---------------------------------------------------------------------------
// Kernel 2: causal attention — round-1 verified compute structure (16 q-rows
// per wave, swapped QK^T, register PV via 16x16x16 MFMA), re-scheduled for
// occupancy: slot = 4 chunks -> 544 jobs/batch, grid 2176 (2x oversubscribed,
// work-conserving backfill), __launch_bounds__(256,6) -> up to 6 blocks/CU
// (VGPR cap 85; measured 84 on the heavier variant).
// ---------------------------------------------------------------------------
__global__ __launch_bounds__(256, 6) void attn_kernel(
    const bf16* __restrict__ kmat,   // [B*T][64]
    const bf16* __restrict__ qvmat,  // [B*T][64]
    const bf16* __restrict__ qvT,    // [B][64][T]
    float* __restrict__ out,         // [B*T][64] raw O partial, slot 0
    float* __restrict__ o_parts,     // [15][B*T][64] raw O partials, slots 1-15
    float* __restrict__ l_parts)     // [16][B*T] l partials
{
    __shared__ bf16 Kt[64][72];      // 9.2 KB
    __shared__ bf16 Vt[64][72];      // 9.2 KB
#if !MFMA16_OK
    __shared__ bf16 plds[4][16][40]; // fallback P staging (80 B rows)
#endif

    const int tid  = threadIdx.x;
    const int lane = tid & 63;
    const int wave = tid >> 6;
    const int col  = lane & 15;
    const int quad = lane >> 4;

    // job decode: 544 jobs/batch, heavy q-blocks first. qb in 0..63 owns 64 q
    // rows and nctot = qb+1 chunks, split into ceil((qb+1)/4) slots of 4.
    const int b = blockIdx.x / 544;
    int r = blockIdx.x - b * 544;
    int qb = 63, jc = 0;
#pragma unroll 1
    for (int q = 63; q >= 0; --q) {
        const int nj = (q + 4) >> 2;             // ceil((q+1)/4)
        if (r < nj) { qb = q; jc = r; break; }
        r -= nj;
    }
    const int nctot = qb + 1;
    const int cbeg  = jc * 4;
    const int cend  = (nctot < cbeg + 4) ? nctot : cbeg + 4;

    const bf16* qvb = qvmat + (size_t)b * T_SEQ * HS;
    const bf16* kb  = kmat  + (size_t)b * T_SEQ * HS;
    const bf16* vTb = qvT   + (size_t)b * HS * T_SEQ;

    const int q0 = qb * 64 + wave * 16;

    // Q fragment: Q[q0+col][d=quad*8+j] — serves as MFMA B-operand (col=lane&15)
    bf16x8 qf0 = *(const bf16x8*)(qvb + (size_t)(q0 + col) * HS + quad * 8);
    bf16x8 qf1 = *(const bf16x8*)(qvb + (size_t)(q0 + col) * HS + 32 + quad * 8);

    f32x4 o[4];
#pragma unroll
    for (int h = 0; h < 4; ++h) o[h] = {0.f, 0.f, 0.f, 0.f};
    float lsum = 0.f;

    const float sc = 0.125f * 1.44269504088896f;

    // register prefetch of first chunk
    bf16x8 kn[2], vn[2];
    {
        const int kc = cbeg * 64;
#pragma unroll
        for (int it = 0; it < 2; ++it) {
            const int idx = it * 256 + tid;
            const int kr  = idx >> 3;
            const int off = (idx & 7) * 8;
            kn[it] = *(const bf16x8*)(kb + (size_t)kc * HS + idx * 8);
            vn[it] = *(const bf16x8*)(vTb + (size_t)kr * T_SEQ + kc + off);
        }
    }

#pragma unroll 1
    for (int c = cbeg; c < cend; ++c) {
        // ---- write prefetched chunk into LDS ----
#pragma unroll
        for (int it = 0; it < 2; ++it) {
            const int idx = it * 256 + tid;
            const int kr  = idx >> 3;
            const int off = (idx & 7) * 8;
            *(bf16x8*)&Kt[kr][off] = kn[it];
            *(bf16x8*)&Vt[kr][off] = vn[it];
        }
        __syncthreads();

        // ---- issue next chunk's loads (hidden behind compute) ----
        if (c + 1 < cend) {
            const int kcn = (c + 1) * 64;
#pragma unroll
            for (int it = 0; it < 2; ++it) {
                const int idx = it * 256 + tid;
                const int kr  = idx >> 3;
                const int off = (idx & 7) * 8;
                kn[it] = *(const bf16x8*)(kb + (size_t)kcn * HS + idx * 8);
                vn[it] = *(const bf16x8*)(vTb + (size_t)kr * T_SEQ + kcn + off);
            }
        }

        // ---- compute chunk c from LDS (swapped: S^T tiles, k=rows q=cols) ----
        const int kc = c * 64;
#pragma unroll
        for (int st = 0; st < 2; ++st) {
            const int gk = kc + 32 * st;
            if (gk > q0 + 15) break;             // fully masked (wave-uniform)

            // K fragments: K[gk + tile*16 + col][d] — serve as A-operand (row=lane&15)
            bf16x8 b0 = *(const bf16x8*)&Kt[32 * st + col][quad * 8];
            bf16x8 b1 = *(const bf16x8*)&Kt[32 * st + col][32 + quad * 8];

            // lane (col=q, quad) gets S^T: P[q0+col][k = gk + tile*16 + quad*4 + r]
            float p0[4], p1[4];
            {
                f32x4 a4 = {0.f, 0.f, 0.f, 0.f};
                a4 = __builtin_amdgcn_mfma_f32_16x16x32_bf16(b0, qf0, a4, 0, 0, 0);
                a4 = __builtin_amdgcn_mfma_f32_16x16x32_bf16(b1, qf1, a4, 0, 0, 0);
#pragma unroll
                for (int i = 0; i < 4; ++i) p0[i] = fexp2(fmaf(a4[i], sc, -24.f));
            }
            const bool do1 = (gk + 16 <= q0 + 15);
            if (do1) {
                bf16x8 b2 = *(const bf16x8*)&Kt[32 * st + 16 + col][quad * 8];
                bf16x8 b3 = *(const bf16x8*)&Kt[32 * st + 16 + col][32 + quad * 8];
                f32x4 a4 = {0.f, 0.f, 0.f, 0.f};
                a4 = __builtin_amdgcn_mfma_f32_16x16x32_bf16(b2, qf0, a4, 0, 0, 0);
                a4 = __builtin_amdgcn_mfma_f32_16x16x32_bf16(b3, qf1, a4, 0, 0, 0);
#pragma unroll
                for (int i = 0; i < 4; ++i) p1[i] = fexp2(fmaf(a4[i], sc, -24.f));
            } else {
#pragma unroll
                for (int i = 0; i < 4; ++i) p1[i] = 0.f;
            }

            if (gk + 31 > q0) {                  // diagonal subtile: mask k > q
#pragma unroll
                for (int i = 0; i < 4; ++i)
                    if (gk + quad * 4 + i > q0 + col) p0[i] = 0.f;
                if (do1) {
#pragma unroll
                    for (int i = 0; i < 4; ++i)
                        if (gk + 16 + quad * 4 + i > q0 + col) p1[i] = 0.f;
                }
            }

            lsum += (p0[0] + p0[1]) + (p0[2] + p0[3]);
            if (do1) lsum += (p1[0] + p1[1]) + (p1[2] + p1[3]);

#if MFMA16_OK
            // PV directly from registers: A-frag of 16x16x16 is k=quad*4+j — matches.
            bf16x4 pa0 = {(bf16)p0[0], (bf16)p0[1], (bf16)p0[2], (bf16)p0[3]};
            s16x4 pa0s = bc4(pa0);
#pragma unroll
            for (int h = 0; h < 4; ++h) {
                bf16x4 vb = *(const bf16x4*)&Vt[h * 16 + col][32 * st + quad * 4];
                o[h] = __builtin_amdgcn_mfma_f32_16x16x16bf16_1k(
                    pa0s, bc4(vb), o[h], 0, 0, 0);
            }
            if (do1) {
                bf16x4 pa1 = {(bf16)p1[0], (bf16)p1[1], (bf16)p1[2], (bf16)p1[3]};
                s16x4 pa1s = bc4(pa1);
#pragma unroll
                for (int h = 0; h < 4; ++h) {
                    bf16x4 vb = *(const bf16x4*)&Vt[h * 16 + col][32 * st + 16 + quad * 4];
                    o[h] = __builtin_amdgcn_mfma_f32_16x16x16bf16_1k(
                        pa1s, bc4(vb), o[h], 0, 0, 0);
                }
            }
#else
            // fallback: [q][k] staging with vectorized b64 writes (wave-private,
            // in-order DS). Always write both halves (p1 zeroed when !do1).
            bf16x4 w0 = {(bf16)p0[0], (bf16)p0[1], (bf16)p0[2], (bf16)p0[3]};
            bf16x4 w1 = {(bf16)p1[0], (bf16)p1[1], (bf16)p1[2], (bf16)p1[3]};
            *(bf16x4*)&plds[wave][col][quad * 4]      = w0;
            *(bf16x4*)&plds[wave][col][16 + quad * 4] = w1;
            bf16x8 pa = *(const bf16x8*)&plds[wave][col][quad * 8];
#pragma unroll
            for (int h = 0; h < 4; ++h) {
                bf16x8 vb = *(const bf16x8*)&Vt[h * 16 + col][32 * st + quad * 8];
                o[h] = __builtin_amdgcn_mfma_f32_16x16x32_bf16(pa, vb, o[h], 0, 0, 0);
            }
#endif
        }
        __syncthreads();   // protect Kt/Vt before next write
    }

    // ---- epilogue ----
    // l: lane holds partial row-sum for q = q0+col; reduce across quads.
    lsum += __shfl_xor(lsum, 16, 64);
    lsum += __shfl_xor(lsum, 32, 64);
    if (quad == 0)
        l_parts[(size_t)jc * 16384 + (size_t)b * T_SEQ + q0 + col] = lsum;

    // O: C layout row=quad*4+i (q-local), col=lane&15 (n within h-group).
    const size_t rowbase = (size_t)b * T_SEQ + q0 + quad * 4;
    float* dst = (jc == 0) ? out : (o_parts + (size_t)(jc - 1) * 16384 * HS);
#pragma unroll
    for (int h = 0; h < 4; ++h)
#pragma unroll
        for (int i = 0; i < 4; ++i)
            dst[(rowbase + i) * HS + h * 16 + col] = o[h][i];
}

// ---------------------------------------------------------------------------
// Kernel 3: combine job partials and normalize: out = sum(O_j) / sum(l_j).
// ---------------------------------------------------------------------------
__global__ __launch_bounds__(256) void norm_kernel(
    float* __restrict__ out,
    const float* __restrict__ o_parts,  // [15][B*T][64]
    const float* __restrict__ l_parts)  // [16][B*T]
{
    const int i   = blockIdx.x * 256 + threadIdx.x;
    const int row = i >> 6;
    const int qb  = (row & 4095) >> 6;
    const int nj  = (qb + 4) >> 2;              // ceil((qb+1)/4)

    float s = out[i];
    float L = l_parts[row];
    for (int j = 1; j < nj; ++j) {
        s += o_parts[(size_t)(j - 1) * 1048576 + i];
        L += l_parts[(size_t)j * 16384 + row];
    }
    out[i] = s / L;
}

extern "C" void kernel_launch(void* const* d_in, const int* in_sizes, int n_in,
                              void* d_out, int out_size, void* d_ws, size_t ws_size,
                              hipStream_t stream) {
    const float* x  = (const float*)d_in[0];
    const float* Wk = (const float*)d_in[1];
    const float* Wv = (const float*)d_in[2];
    float* out = (float*)d_out;

    bf16* ws    = (bf16*)d_ws;
    bf16* wbf   = ws;                                    // 256 KB
    bf16* kmat  = ws + (size_t)128 * 1024;               // 2 MB
    bf16* qvmat = kmat + (size_t)16384 * 64;             // 2 MB
    bf16* qvT   = qvmat + (size_t)16384 * 64;            // 2 MB
    float* o_parts = (float*)(qvT + (size_t)16384 * 64); // 60 MB (slots 1-15)
    float* l_parts = o_parts + (size_t)15 * 16384 * 64;  // 1 MB

    wcast_kernel<<<64, 256, 0, stream>>>(Wk, Wv, wbf);
    proj_kernel<<<512, 256, 0, stream>>>(x, wbf, kmat, qvmat, qvT);
    attn_kernel<<<2176, 256, 0, stream>>>(kmat, qvmat, qvT, out, o_parts, l_parts);
    norm_kernel<<<4096, 256, 0, stream>>>(out, o_parts, l_parts);
}